// Round 8
// baseline (1061.293 us; speedup 1.0000x reference)
//
#include <hip/hip_runtime.h>
#include <hip/hip_bf16.h>
#include <math.h>

#define N_NODES_C 50000
#define N_EDGES_C 800000
#define NFEAT_C 512
#define NH_C 128
#define NLAYERS_C 16
#define LDB 136  // padded LDS row stride (u16); 136*2=272B = 16B-aligned per row

typedef __attribute__((ext_vector_type(8))) short short8;
typedef __attribute__((ext_vector_type(4))) float f32x4;
typedef unsigned int u32x4 __attribute__((ext_vector_type(4)));  // nt-capable 16B

__device__ __forceinline__ float b2f(unsigned short h) {
    union { unsigned int u; float f; } v; v.u = ((unsigned int)h) << 16; return v.f;
}
__device__ __forceinline__ unsigned short f2b(float f) {
    union { float f; unsigned int u; } v; v.f = f;
    unsigned int r = (v.u + 0x7fffu + ((v.u >> 16) & 1u)) >> 16;
    return (unsigned short)r;
}

// non-temporal 16B helpers: intermediates (hs/sout/hdst) are produced on one
// XCD and consumed chip-wide next kernel; nt stores retire lines to L3/HBM
// instead of leaving them dirty in the producer XCD's L2 (cross-XCD dirty-line
// service is the slow path). nt loads keep one-shot streams from evicting
// gather-reusable lines. Cache hints only — bit-identical results.
// NOTE: builtin requires native vector types -> u32x4 (ext_vector_type), not
// HIP_vector_type uint4 (R7 compile failure).
__device__ __forceinline__ u32x4 ntload4(const void* p) {
    return __builtin_nontemporal_load((const u32x4*)p);
}
__device__ __forceinline__ void ntstore4(void* p, u32x4 v) {
    __builtin_nontemporal_store(v, (u32x4*)p);
}

// ---------------- CSR build (validated R3≡R5≡R6 bit-identity) ----------------

__global__ __launch_bounds__(256) void k_count(const int* __restrict__ row,
                                               int* __restrict__ cnt) {
    int e = blockIdx.x * 256 + threadIdx.x;
    atomicAdd(&cnt[row[e]], 1);
}

__global__ __launch_bounds__(256) void k_scan1(const int* __restrict__ cnt,
                                               int* __restrict__ locex,
                                               int* __restrict__ partials, int n) {
    __shared__ int sm[256];
    int t = threadIdx.x;
    int i = blockIdx.x * 256 + t;
    int v = (i < n) ? cnt[i] : 0;
    sm[t] = v;
    __syncthreads();
    for (int o = 1; o < 256; o <<= 1) {
        int x = (t >= o) ? sm[t - o] : 0;
        __syncthreads();
        sm[t] += x;
        __syncthreads();
    }
    if (i < n) locex[i] = sm[t] - v;
    if (t == 255) partials[blockIdx.x] = sm[255];
}

__global__ __launch_bounds__(256) void k_scan2(int* __restrict__ partials, int np) {
    __shared__ int sm[256];
    int t = threadIdx.x;
    int v = (t < np) ? partials[t] : 0;
    sm[t] = v;
    __syncthreads();
    for (int o = 1; o < 256; o <<= 1) {
        int x = (t >= o) ? sm[t - o] : 0;
        __syncthreads();
        sm[t] += x;
        __syncthreads();
    }
    if (t < np) partials[t] = sm[t] - v;
}

__global__ __launch_bounds__(256) void k_scan3(const int* __restrict__ cnt,
                                               const int* __restrict__ locex,
                                               const int* __restrict__ partials,
                                               int* __restrict__ rowptr,
                                               int* __restrict__ cursor,
                                               float* __restrict__ dinv,
                                               int n, int ne) {
    int i = blockIdx.x * 256 + threadIdx.x;
    if (i < n) {
        int rp = locex[i] + partials[i >> 8];
        rowptr[i] = rp;
        cursor[i] = rp;
        dinv[i] = 1.0f / sqrtf((float)(cnt[i] + 1));  // +1 self loop
    }
    if (i == 0) rowptr[n] = ne;
}

__global__ __launch_bounds__(256) void k_fill(const int* __restrict__ row,
                                              const int* __restrict__ col,
                                              int* __restrict__ cursor,
                                              int* __restrict__ colsorted) {
    int e = blockIdx.x * 256 + threadIdx.x;
    int p = atomicAdd(&cursor[row[e]], 1);
    colsorted[p] = col[e];
}

// ---------------- weight transpose+convert: fp32 [K][128] -> bf16 T [128][K] ---

__global__ __launch_bounds__(256) void k_convt128(const float* __restrict__ src,
                                                  unsigned short* __restrict__ dst,
                                                  int total) {  // L x 128 x 128
    int i = blockIdx.x * 256 + threadIdx.x;
    if (i >= total) return;
    int l = i >> 14, w = i & 16383;
    int n = w >> 7, k = w & 127;
    dst[i] = f2b(src[(l << 14) + (k << 7) + n]);
}

__global__ __launch_bounds__(256) void k_convt_fc0(const float* __restrict__ src,
                                                   unsigned short* __restrict__ dst) {
    int i = blockIdx.x * 256 + threadIdx.x;  // total 65536
    int n = i >> 9, k = i & 511;
    dst[i] = f2b(src[(k << 7) + n]);
}

// ---------------- SpMM + support (R3-proven form + nt hints) ------------------
// s[r] = 0.9*dinv[r]*(sum_c hs[c] + hs[r]) + 0.1*h0[r]
// 1 wave/row, 4 groups x 16 lanes; each group gathers a DIFFERENT edge with
// dwordx4 (16B/lane): one load instruction = 4 full rows; 16 edges / 4KB in
// flight. Gather loads stay NORMAL (want L2 caching of 16x col reuse); h0
// stream = nt load; sout = nt store.

__device__ __forceinline__ void acc8(float* a, uint4 u) {
    a[0] += b2f((unsigned short)(u.x & 0xffffu));
    a[1] += b2f((unsigned short)(u.x >> 16));
    a[2] += b2f((unsigned short)(u.y & 0xffffu));
    a[3] += b2f((unsigned short)(u.y >> 16));
    a[4] += b2f((unsigned short)(u.z & 0xffffu));
    a[5] += b2f((unsigned short)(u.z >> 16));
    a[6] += b2f((unsigned short)(u.w & 0xffffu));
    a[7] += b2f((unsigned short)(u.w >> 16));
}

__global__ __launch_bounds__(256) void k_spmm(const unsigned short* __restrict__ hs,
                                              const unsigned short* __restrict__ h0,
                                              const float* __restrict__ dinv,
                                              const int* __restrict__ rowptr,
                                              const int* __restrict__ cols,
                                              unsigned short* __restrict__ sout) {
    const int w = threadIdx.x >> 6, ln = threadIdx.x & 63;
    const int r = blockIdx.x * 4 + w;
    const int g = ln >> 4, gi = ln & 15;  // group, 16B-slot within row
    const uint4* hs4 = (const uint4*)hs;  // 16 x uint4 per 128-feature row
    const uint4* h04 = (const uint4*)h0;

    float a[8];
#pragma unroll
    for (int j = 0; j < 8; j++) a[j] = 0.f;

    int e = rowptr[r];
    const int end = rowptr[r + 1];

    // self loop -> group 0's partial
    if (g == 0) {
        uint4 u = hs4[(size_t)r * 16 + gi];
        acc8(a, u);
    }
    // main: 16 edges per iteration, 4 dwordx4 gathers in flight
    for (; e + 15 < end; e += 16) {
        int cA = cols[e + g];
        int cB = cols[e + 4 + g];
        int cC = cols[e + 8 + g];
        int cD = cols[e + 12 + g];
        uint4 uA = hs4[(size_t)cA * 16 + gi];
        uint4 uB = hs4[(size_t)cB * 16 + gi];
        uint4 uC = hs4[(size_t)cC * 16 + gi];
        uint4 uD = hs4[(size_t)cD * 16 + gi];
        acc8(a, uA);
        acc8(a, uB);
        acc8(a, uC);
        acc8(a, uD);
    }
    // 4-edge steps
    for (; e + 3 < end; e += 4) {
        int c = cols[e + g];
        uint4 u = hs4[(size_t)c * 16 + gi];
        acc8(a, u);
    }
    // remainder (<4): group g takes edge e+g if it exists
    int rem = end - e;
    if (g < rem) {
        int c = cols[e + g];
        uint4 u = hs4[(size_t)c * 16 + gi];
        acc8(a, u);
    }

    // combine the 4 group partials (after: all lanes hold full sums)
#pragma unroll
    for (int j = 0; j < 8; j++) {
        a[j] += __shfl_xor(a[j], 16);
        a[j] += __shfl_xor(a[j], 32);
    }

    float dr = 0.9f * dinv[r];
    u32x4 hv = ntload4(&h04[(size_t)r * 16 + gi]);
    u32x4 o;
    o.x = (unsigned int)f2b(dr * a[0] + 0.1f * b2f((unsigned short)(hv.x & 0xffffu))) |
          ((unsigned int)f2b(dr * a[1] + 0.1f * b2f((unsigned short)(hv.x >> 16))) << 16);
    o.y = (unsigned int)f2b(dr * a[2] + 0.1f * b2f((unsigned short)(hv.y & 0xffffu))) |
          ((unsigned int)f2b(dr * a[3] + 0.1f * b2f((unsigned short)(hv.y >> 16))) << 16);
    o.z = (unsigned int)f2b(dr * a[4] + 0.1f * b2f((unsigned short)(hv.z & 0xffffu))) |
          ((unsigned int)f2b(dr * a[5] + 0.1f * b2f((unsigned short)(hv.z >> 16))) << 16);
    o.w = (unsigned int)f2b(dr * a[6] + 0.1f * b2f((unsigned short)(hv.w & 0xffffu))) |
          ((unsigned int)f2b(dr * a[7] + 0.1f * b2f((unsigned short)(hv.w >> 16))) << 16);
    if (g == 0) ntstore4(&((uint4*)sout)[(size_t)r * 16 + gi], o);
}

// ---------------- layer GEMM+blend (R3-proven + nt hints) ---------------------
// out[r] = relu(theta*(s@W) + (1-theta)*s[r]) * (use_dinv?dinv[r]:1)
// 4 waves; wave w owns rows w*16..w*16+15 across ALL 128 cols (wave-private
// rows -> barrier-free in-place blend epilogue stays legal). S staging = nt
// load (one-shot stream, freshly written cross-XCD); hdst = nt store (next
// consumed chip-wide by spmm gather). WT loads stay normal (L2-hot, reused).

__global__ __launch_bounds__(256) void k_gemm_blend(
    const unsigned short* __restrict__ S, const float* __restrict__ dinv,
    const unsigned short* __restrict__ WT, unsigned short* __restrict__ hdst,
    float theta, int use_dinv) {
    __shared__ __align__(16) unsigned short s_lds[64 * LDB];
    __shared__ __align__(16) unsigned short bt[128 * LDB];
    const int tid = threadIdx.x;
    const int w = tid >> 6, ln = tid & 63;
    const int quad = ln >> 4, l16 = ln & 15;
    const int block_base = blockIdx.x * 64;

    // stage WT (128x128) and S tile (64x128); conflict-free b128
    for (int chunk = tid; chunk < 128 * 16; chunk += 256) {
        int n = chunk >> 4, k8 = (chunk & 15) << 3;
        *(short8*)&bt[n * LDB + k8] = *(const short8*)&WT[(n << 7) + k8];
    }
    for (int chunk = tid; chunk < 64 * 16; chunk += 256) {
        int n = chunk >> 4, k8 = (chunk & 15) << 3;
        int row = block_base + n;
        u32x4 v = {0u, 0u, 0u, 0u};
        if (row < N_NODES_C)
            v = ntload4(&S[(size_t)row * NH_C + k8]);
        *(u32x4*)&s_lds[n * LDB + k8] = v;
    }
    __syncthreads();

    // MFMA: wave w computes rows w*16..w*16+15, all 128 output cols
    f32x4 acc[8];
#pragma unroll
    for (int j = 0; j < 8; j++) acc[j] = (f32x4){0.f, 0.f, 0.f, 0.f};
#pragma unroll
    for (int ki = 0; ki < 128; ki += 32) {
        short8 af = *(const short8*)&s_lds[((w << 4) + l16) * LDB + ki + quad * 8];
#pragma unroll
        for (int nt = 0; nt < 8; nt++) {
            short8 bf = *(const short8*)&bt[(nt * 16 + l16) * LDB + ki + quad * 8];
            acc[nt] = __builtin_amdgcn_mfma_f32_16x16x32_bf16(af, bf, acc[nt], 0, 0, 0);
        }
    }

    // blend epilogue (C-layout col=l16,row=quad*4+reg); wave-private rows ->
    // safe to overwrite s_lds in place without a barrier
#pragma unroll
    for (int reg = 0; reg < 4; reg++) {
        int lr = (w << 4) + (quad << 2) + reg;
        int r = block_base + lr;
        float drv = dinv[(r < N_NODES_C) ? r : (N_NODES_C - 1)];
#pragma unroll
        for (int nt = 0; nt < 8; nt++) {
            int n = nt * 16 + l16;
            float s = b2f(s_lds[lr * LDB + n]);
            float v = theta * acc[nt][reg] + (1.f - theta) * s;
            v = fmaxf(v, 0.f);
            if (use_dinv) v *= drv;
            s_lds[lr * LDB + n] = f2b(v);
        }
    }
    __syncthreads();
    // coalesced b128 nt stores
    for (int chunk = tid; chunk < 64 * 16; chunk += 256) {
        int lr = chunk >> 4, c8 = (chunk & 15) << 3;
        int row = block_base + lr;
        if (row < N_NODES_C) {
            u32x4 v = *(const u32x4*)&s_lds[lr * LDB + c8];
            ntstore4(&hdst[(size_t)row * NH_C + c8], v);
        }
    }
}

// ---------------- MFMA GEMM (fc0 / fc1) ---------------------------------------
// WT: bf16 [128][K]. mode 0: h0/hs outputs (LDS-bounce, nt stores); mode 2:
// fp32 out. R2/R6 lessons: keep WT staged in LDS + per-fragment A loads —
// staging A instead just moves the 16-lane scatter onto WT (R6: 94µs).

template <int AFP32, int MT>
__global__ __launch_bounds__(256) void k_gemm(
    const void* __restrict__ Av, const unsigned short* __restrict__ WT,
    int M, int K,
    const float* __restrict__ bias, const float* __restrict__ dinv,
    unsigned short* __restrict__ out0, unsigned short* __restrict__ out1,
    float* __restrict__ outf, int mode) {
    __shared__ __align__(16) unsigned short bt[128 * LDB];
    const int tid = threadIdx.x;
    const int w = tid >> 6, ln = tid & 63;
    const int quad = ln >> 4, l16 = ln & 15;
    const int ROWS = 64 * MT;
    const int block_base = blockIdx.x * ROWS;
    const int m_base = block_base + w * (16 * MT);

    f32x4 acc[MT][8];
#pragma unroll
    for (int i = 0; i < MT; i++)
#pragma unroll
        for (int j = 0; j < 8; j++) acc[i][j] = (f32x4){0.f, 0.f, 0.f, 0.f};

    for (int kc = 0; kc < K; kc += 128) {
        for (int chunk = tid; chunk < 128 * 16; chunk += 256) {
            int n = chunk >> 4, k8 = (chunk & 15) << 3;
            *(short8*)&bt[n * LDB + k8] = *(const short8*)&WT[(size_t)n * K + kc + k8];
        }
        __syncthreads();
#pragma unroll
        for (int ki = 0; ki < 128; ki += 32) {
            short8 bf[8];
#pragma unroll
            for (int nt = 0; nt < 8; nt++)
                bf[nt] = *(const short8*)&bt[(nt * 16 + l16) * LDB + ki + quad * 8];
#pragma unroll
            for (int mt = 0; mt < MT; mt++) {
                int row = m_base + mt * 16 + l16;
                if (row >= M) row = M - 1;
                short8 af;
                if (AFP32) {
                    const float* A = (const float*)Av;
                    const float* p = &A[(size_t)row * K + kc + ki + quad * 8];
                    float4 f0 = *(const float4*)p;
                    float4 f1 = *(const float4*)(p + 4);
                    af[0] = (short)f2b(f0.x); af[1] = (short)f2b(f0.y);
                    af[2] = (short)f2b(f0.z); af[3] = (short)f2b(f0.w);
                    af[4] = (short)f2b(f1.x); af[5] = (short)f2b(f1.y);
                    af[6] = (short)f2b(f1.z); af[7] = (short)f2b(f1.w);
                } else {
                    const unsigned short* A = (const unsigned short*)Av;
                    af = *(const short8*)&A[(size_t)row * K + kc + ki + quad * 8];
                }
#pragma unroll
                for (int nt = 0; nt < 8; nt++)
                    acc[mt][nt] = __builtin_amdgcn_mfma_f32_16x16x32_bf16(
                        af, bf[nt], acc[mt][nt], 0, 0, 0);
            }
        }
        __syncthreads();
    }

    if (mode == 2) {
#pragma unroll
        for (int mt = 0; mt < MT; mt++)
#pragma unroll
            for (int reg = 0; reg < 4; reg++) {
                int r = m_base + mt * 16 + quad * 4 + reg;
                if (r >= M) continue;
#pragma unroll
                for (int nt = 0; nt < 8; nt++) {
                    int n = nt * 16 + l16;
                    outf[(size_t)r * NH_C + n] = acc[mt][nt][reg] + bias[n];
                }
            }
        return;
    }

    // mode 0: relu(acc+bias) -> LDS -> coalesced h0/hs nt stores
#pragma unroll
    for (int mt = 0; mt < MT; mt++)
#pragma unroll
        for (int reg = 0; reg < 4; reg++) {
            int lr = w * (16 * MT) + mt * 16 + quad * 4 + reg;
#pragma unroll
            for (int nt = 0; nt < 8; nt++) {
                int n = nt * 16 + l16;
                float v = acc[mt][nt][reg] + bias[n];
                bt[lr * LDB + n] = f2b(fmaxf(v, 0.f));
            }
        }
    __syncthreads();
    for (int chunk = tid; chunk < ROWS * 16; chunk += 256) {
        int lr = chunk >> 4, c8 = (chunk & 15) << 3;
        int row = block_base + lr;
        if (row >= M) continue;
        short8 v = *(const short8*)&bt[lr * LDB + c8];
        {
            u32x4 u = *(const u32x4*)&bt[lr * LDB + c8];
            ntstore4(&out1[(size_t)row * NH_C + c8], u);  // h0
        }
        float dr = dinv[row];
        short8 o;
#pragma unroll
        for (int j = 0; j < 8; j++)
            o[j] = (short)f2b(b2f((unsigned short)v[j]) * dr);
        union { short8 s; u32x4 u; } cv;
        cv.s = o;
        ntstore4(&out0[(size_t)row * NH_C + c8], cv.u);  // hs
    }
}

// ---------------- host ----------------

extern "C" void kernel_launch(void* const* d_in, const int* in_sizes, int n_in,
                              void* d_out, int out_size, void* d_ws, size_t ws_size,
                              hipStream_t stream) {
    const float* x = (const float*)d_in[0];
    const int* edge = (const int*)d_in[1];
    const float* convw = (const float*)d_in[2];
    const float* fc0w = (const float*)d_in[3];
    const float* fc0b = (const float*)d_in[4];
    const float* fc1w = (const float*)d_in[5];
    const float* fc1b = (const float*)d_in[6];
    const int* erow = edge;
    const int* ecol = edge + N_EDGES_C;

    char* ws = (char*)d_ws;
    size_t off = 0;
    auto alloc = [&](size_t bytes) -> void* {
        off = (off + 255) & ~(size_t)255;
        void* p = ws + off;
        off += bytes;
        return p;
    };
    int* cnt = (int*)alloc(N_NODES_C * 4);
    int* cursor = (int*)alloc(N_NODES_C * 4);
    int* locex = (int*)alloc(N_NODES_C * 4);
    int* partials = (int*)alloc(1024);
    int* rowptr = (int*)alloc((N_NODES_C + 1) * 4);
    float* dinv = (float*)alloc(N_NODES_C * 4);
    int* colsorted = (int*)alloc(N_EDGES_C * 4);
    unsigned short* wconvT = (unsigned short*)alloc((size_t)NLAYERS_C * NH_C * NH_C * 2);
    unsigned short* wfc0T = (unsigned short*)alloc((size_t)NFEAT_C * NH_C * 2);
    unsigned short* wfc1T = (unsigned short*)alloc((size_t)NH_C * NH_C * 2);
    unsigned short* h0 = (unsigned short*)alloc((size_t)N_NODES_C * NH_C * 2);
    unsigned short* hsA = (unsigned short*)alloc((size_t)N_NODES_C * NH_C * 2);
    unsigned short* hsB = (unsigned short*)alloc((size_t)N_NODES_C * NH_C * 2);
    unsigned short* sbuf = (unsigned short*)alloc((size_t)N_NODES_C * NH_C * 2);
    (void)ws_size; (void)n_in; (void)in_sizes; (void)out_size;

    // weights -> transposed bf16
    k_convt128<<<NLAYERS_C * NH_C * NH_C / 256, 256, 0, stream>>>(
        convw, wconvT, NLAYERS_C * NH_C * NH_C);
    k_convt_fc0<<<NFEAT_C * NH_C / 256, 256, 0, stream>>>(fc0w, wfc0T);
    k_convt128<<<NH_C * NH_C / 256, 256, 0, stream>>>(fc1w, wfc1T, NH_C * NH_C);

    // CSR build
    hipMemsetAsync(cnt, 0, N_NODES_C * 4, stream);
    k_count<<<N_EDGES_C / 256, 256, 0, stream>>>(erow, cnt);
    const int NB = (N_NODES_C + 255) / 256;  // 196
    k_scan1<<<NB, 256, 0, stream>>>(cnt, locex, partials, N_NODES_C);
    k_scan2<<<1, 256, 0, stream>>>(partials, NB);
    k_scan3<<<NB, 256, 0, stream>>>(cnt, locex, partials, rowptr, cursor, dinv,
                                    N_NODES_C, N_EDGES_C);
    k_fill<<<N_EDGES_C / 256, 256, 0, stream>>>(erow, ecol, cursor, colsorted);

    const int GB1 = (N_NODES_C + 63) / 64;    // 782
    // fc0: h0 = relu(x@fc0_w + b); hsA = dinv .* h0  (R1-proven 62µs form)
    k_gemm<1, 1><<<GB1, 256, 0, stream>>>(x, wfc0T, N_NODES_C, NFEAT_C, fc0b, dinv,
                                          hsA, h0, nullptr, 0);
    unsigned short* cur = hsA;
    unsigned short* nxt = hsB;
    for (int l = 0; l < NLAYERS_C; l++) {
        k_spmm<<<N_NODES_C / 4, 256, 0, stream>>>(cur, h0, dinv, rowptr, colsorted,
                                                  sbuf);
        float theta = logf(0.5f / (float)(l + 1) + 1.0f);
        k_gemm_blend<<<GB1, 256, 0, stream>>>(sbuf, dinv,
                                              wconvT + (size_t)l * NH_C * NH_C, nxt,
                                              theta, (l < NLAYERS_C - 1) ? 1 : 0);
        unsigned short* t = cur; cur = nxt; nxt = t;
    }
    // fc1: out = h@fc1_w + b -> fp32
    k_gemm<0, 1><<<GB1, 256, 0, stream>>>(cur, wfc1T, N_NODES_C, NH_C, fc1b, dinv,
                                          nullptr, nullptr, (float*)d_out, 2);
}

// Round 9
// 1004.437 us; speedup vs baseline: 1.0566x; 1.0566x over previous
//
#include <hip/hip_runtime.h>
#include <hip/hip_bf16.h>
#include <math.h>

#define N_NODES_C 50000
#define N_EDGES_C 800000
#define NFEAT_C 512
#define NH_C 128
#define NLAYERS_C 16
#define LDB 136  // padded LDS row stride (u16)

typedef __attribute__((ext_vector_type(8))) short short8;
typedef __attribute__((ext_vector_type(4))) float f32x4;

__device__ __forceinline__ float b2f(unsigned short h) {
    union { unsigned int u; float f; } v; v.u = ((unsigned int)h) << 16; return v.f;
}
__device__ __forceinline__ unsigned short f2b(float f) {
    union { float f; unsigned int u; } v; v.f = f;
    unsigned int r = (v.u + 0x7fffu + ((v.u >> 16) & 1u)) >> 16;
    return (unsigned short)r;
}

// ---------------- CSR build (validated R3≡R5≡R6 bit-identity) ----------------

__global__ __launch_bounds__(256) void k_count(const int* __restrict__ row,
                                               int* __restrict__ cnt) {
    int e = blockIdx.x * 256 + threadIdx.x;
    atomicAdd(&cnt[row[e]], 1);
}

__global__ __launch_bounds__(256) void k_scan1(const int* __restrict__ cnt,
                                               int* __restrict__ locex,
                                               int* __restrict__ partials, int n) {
    __shared__ int sm[256];
    int t = threadIdx.x;
    int i = blockIdx.x * 256 + t;
    int v = (i < n) ? cnt[i] : 0;
    sm[t] = v;
    __syncthreads();
    for (int o = 1; o < 256; o <<= 1) {
        int x = (t >= o) ? sm[t - o] : 0;
        __syncthreads();
        sm[t] += x;
        __syncthreads();
    }
    if (i < n) locex[i] = sm[t] - v;
    if (t == 255) partials[blockIdx.x] = sm[255];
}

__global__ __launch_bounds__(256) void k_scan2(int* __restrict__ partials, int np) {
    __shared__ int sm[256];
    int t = threadIdx.x;
    int v = (t < np) ? partials[t] : 0;
    sm[t] = v;
    __syncthreads();
    for (int o = 1; o < 256; o <<= 1) {
        int x = (t >= o) ? sm[t - o] : 0;
        __syncthreads();
        sm[t] += x;
        __syncthreads();
    }
    if (t < np) partials[t] = sm[t] - v;
}

__global__ __launch_bounds__(256) void k_scan3(const int* __restrict__ cnt,
                                               const int* __restrict__ locex,
                                               const int* __restrict__ partials,
                                               int* __restrict__ rowptr,
                                               int* __restrict__ cursor,
                                               float* __restrict__ dinv,
                                               int n, int ne) {
    int i = blockIdx.x * 256 + threadIdx.x;
    if (i < n) {
        int rp = locex[i] + partials[i >> 8];
        rowptr[i] = rp;
        cursor[i] = rp;
        dinv[i] = 1.0f / sqrtf((float)(cnt[i] + 1));  // +1 self loop
    }
    if (i == 0) rowptr[n] = ne;
}

__global__ __launch_bounds__(256) void k_fill(const int* __restrict__ row,
                                              const int* __restrict__ col,
                                              int* __restrict__ cursor,
                                              int* __restrict__ colsorted) {
    int e = blockIdx.x * 256 + threadIdx.x;
    int p = atomicAdd(&cursor[row[e]], 1);
    colsorted[p] = col[e];
}

// ---------------- weight transpose+convert: fp32 [K][128] -> bf16 T [128][K] ---

__global__ __launch_bounds__(256) void k_convt128(const float* __restrict__ src,
                                                  unsigned short* __restrict__ dst,
                                                  int total) {  // L x 128 x 128
    int i = blockIdx.x * 256 + threadIdx.x;
    if (i >= total) return;
    int l = i >> 14, w = i & 16383;
    int n = w >> 7, k = w & 127;
    dst[i] = f2b(src[(l << 14) + (k << 7) + n]);
}

__global__ __launch_bounds__(256) void k_convt_fc0(const float* __restrict__ src,
                                                   unsigned short* __restrict__ dst) {
    int i = blockIdx.x * 256 + threadIdx.x;  // total 65536
    int n = i >> 9, k = i & 511;
    dst[i] = f2b(src[(k << 7) + n]);
}

// ---------------- SpMM + support (R3-proven form; nt hints REVERTED) ----------
// s[r] = 0.9*dinv[r]*(sum_c hs[c] + hs[r]) + 0.1*h0[r]
// 1 wave/row, 4 groups x 16 lanes; each group gathers a DIFFERENT edge with
// dwordx4 (16B/lane): one load instruction = 4 full rows; 16 edges / 4KB in
// flight. R8 lesson: __builtin_nontemporal demotes past L3 -> consumers pay
// HBM latency; normal cached stores/loads are faster here.

__device__ __forceinline__ void acc8(float* a, uint4 u) {
    a[0] += b2f((unsigned short)(u.x & 0xffffu));
    a[1] += b2f((unsigned short)(u.x >> 16));
    a[2] += b2f((unsigned short)(u.y & 0xffffu));
    a[3] += b2f((unsigned short)(u.y >> 16));
    a[4] += b2f((unsigned short)(u.z & 0xffffu));
    a[5] += b2f((unsigned short)(u.z >> 16));
    a[6] += b2f((unsigned short)(u.w & 0xffffu));
    a[7] += b2f((unsigned short)(u.w >> 16));
}

__global__ __launch_bounds__(256) void k_spmm(const unsigned short* __restrict__ hs,
                                              const unsigned short* __restrict__ h0,
                                              const float* __restrict__ dinv,
                                              const int* __restrict__ rowptr,
                                              const int* __restrict__ cols,
                                              unsigned short* __restrict__ sout) {
    const int w = threadIdx.x >> 6, ln = threadIdx.x & 63;
    const int r = blockIdx.x * 4 + w;
    const int g = ln >> 4, gi = ln & 15;  // group, 16B-slot within row
    const uint4* hs4 = (const uint4*)hs;  // 16 x uint4 per 128-feature row
    const uint4* h04 = (const uint4*)h0;

    float a[8];
#pragma unroll
    for (int j = 0; j < 8; j++) a[j] = 0.f;

    int e = rowptr[r];
    const int end = rowptr[r + 1];

    // self loop -> group 0's partial
    if (g == 0) {
        uint4 u = hs4[(size_t)r * 16 + gi];
        acc8(a, u);
    }
    // main: 16 edges per iteration, 4 dwordx4 gathers in flight
    for (; e + 15 < end; e += 16) {
        int cA = cols[e + g];
        int cB = cols[e + 4 + g];
        int cC = cols[e + 8 + g];
        int cD = cols[e + 12 + g];
        uint4 uA = hs4[(size_t)cA * 16 + gi];
        uint4 uB = hs4[(size_t)cB * 16 + gi];
        uint4 uC = hs4[(size_t)cC * 16 + gi];
        uint4 uD = hs4[(size_t)cD * 16 + gi];
        acc8(a, uA);
        acc8(a, uB);
        acc8(a, uC);
        acc8(a, uD);
    }
    // 4-edge steps
    for (; e + 3 < end; e += 4) {
        int c = cols[e + g];
        uint4 u = hs4[(size_t)c * 16 + gi];
        acc8(a, u);
    }
    // remainder (<4): group g takes edge e+g if it exists
    int rem = end - e;
    if (g < rem) {
        int c = cols[e + g];
        uint4 u = hs4[(size_t)c * 16 + gi];
        acc8(a, u);
    }

    // combine the 4 group partials (after: all lanes hold full sums)
#pragma unroll
    for (int j = 0; j < 8; j++) {
        a[j] += __shfl_xor(a[j], 16);
        a[j] += __shfl_xor(a[j], 32);
    }

    float dr = 0.9f * dinv[r];
    uint4 hv = h04[(size_t)r * 16 + gi];
    uint4 o;
    o.x = (unsigned int)f2b(dr * a[0] + 0.1f * b2f((unsigned short)(hv.x & 0xffffu))) |
          ((unsigned int)f2b(dr * a[1] + 0.1f * b2f((unsigned short)(hv.x >> 16))) << 16);
    o.y = (unsigned int)f2b(dr * a[2] + 0.1f * b2f((unsigned short)(hv.y & 0xffffu))) |
          ((unsigned int)f2b(dr * a[3] + 0.1f * b2f((unsigned short)(hv.y >> 16))) << 16);
    o.z = (unsigned int)f2b(dr * a[4] + 0.1f * b2f((unsigned short)(hv.z & 0xffffu))) |
          ((unsigned int)f2b(dr * a[5] + 0.1f * b2f((unsigned short)(hv.z >> 16))) << 16);
    o.w = (unsigned int)f2b(dr * a[6] + 0.1f * b2f((unsigned short)(hv.w & 0xffffu))) |
          ((unsigned int)f2b(dr * a[7] + 0.1f * b2f((unsigned short)(hv.w >> 16))) << 16);
    if (g == 0) ((uint4*)sout)[(size_t)r * 16 + gi] = o;
}

// ---------------- layer GEMM+blend (R3 structure, barrier-free epilogue) ------
// out[r] = relu(theta*(s@W) + (1-theta)*s[r]) * (use_dinv?dinv[r]:1)
// 4 waves; wave w owns rows w*16..w*16+15 across ALL 128 cols. R9: store loop
// remapped so each wave stores ITS OWN rows (lr = w*16 + local>>4) -> the
// blend-write -> store-read LDS chain is wave-private -> post-blend
// __syncthreads() deleted (in-wave lgkmcnt ordering suffices).

__global__ __launch_bounds__(256) void k_gemm_blend(
    const unsigned short* __restrict__ S, const float* __restrict__ dinv,
    const unsigned short* __restrict__ WT, unsigned short* __restrict__ hdst,
    float theta, int use_dinv) {
    __shared__ __align__(16) unsigned short s_lds[64 * LDB];
    __shared__ __align__(16) unsigned short bt[128 * LDB];
    const int tid = threadIdx.x;
    const int w = tid >> 6, ln = tid & 63;
    const int quad = ln >> 4, l16 = ln & 15;
    const int block_base = blockIdx.x * 64;

    // stage WT (128x128) and S tile (64x128); conflict-free b128
    for (int chunk = tid; chunk < 128 * 16; chunk += 256) {
        int n = chunk >> 4, k8 = (chunk & 15) << 3;
        *(short8*)&bt[n * LDB + k8] = *(const short8*)&WT[(n << 7) + k8];
    }
    for (int chunk = tid; chunk < 64 * 16; chunk += 256) {
        int n = chunk >> 4, k8 = (chunk & 15) << 3;
        int row = block_base + n;
        short8 v = {};
        if (row < N_NODES_C) v = *(const short8*)&S[(size_t)row * NH_C + k8];
        *(short8*)&s_lds[n * LDB + k8] = v;
    }
    __syncthreads();

    // MFMA: wave w computes rows w*16..w*16+15, all 128 output cols
    f32x4 acc[8];
#pragma unroll
    for (int j = 0; j < 8; j++) acc[j] = (f32x4){0.f, 0.f, 0.f, 0.f};
#pragma unroll
    for (int ki = 0; ki < 128; ki += 32) {
        short8 af = *(const short8*)&s_lds[((w << 4) + l16) * LDB + ki + quad * 8];
#pragma unroll
        for (int nt = 0; nt < 8; nt++) {
            short8 bf = *(const short8*)&bt[(nt * 16 + l16) * LDB + ki + quad * 8];
            acc[nt] = __builtin_amdgcn_mfma_f32_16x16x32_bf16(af, bf, acc[nt], 0, 0, 0);
        }
    }

    // blend epilogue (C-layout col=l16,row=quad*4+reg); wave-private rows ->
    // in-place overwrite of s_lds, no barrier
#pragma unroll
    for (int reg = 0; reg < 4; reg++) {
        int lr = (w << 4) + (quad << 2) + reg;
        int r = block_base + lr;
        float drv = dinv[(r < N_NODES_C) ? r : (N_NODES_C - 1)];
#pragma unroll
        for (int nt = 0; nt < 8; nt++) {
            int n = nt * 16 + l16;
            float s = b2f(s_lds[lr * LDB + n]);
            float v = theta * acc[nt][reg] + (1.f - theta) * s;
            v = fmaxf(v, 0.f);
            if (use_dinv) v *= drv;
            s_lds[lr * LDB + n] = f2b(v);
        }
    }
    // wave-private coalesced b128 stores (no barrier: same wave wrote these rows)
#pragma unroll
    for (int it = 0; it < 4; it++) {
        int local = ln + it * 64;
        int lr = (w << 4) + (local >> 4);
        int c8 = (local & 15) << 3;
        int row = block_base + lr;
        if (row < N_NODES_C)
            *(short8*)&hdst[(size_t)row * NH_C + c8] = *(const short8*)&s_lds[lr * LDB + c8];
    }
}

// ---------------- MFMA GEMM (fc0 / fc1) ---------------------------------------
// WT: bf16 [128][K], staged in LDS (R2/R6: staging A instead loses). R9: A
// loads for the WHOLE kc-block are hoisted ahead of WT staging + barrier —
// they issue first, land during the barrier's vmcnt drain, so the A-load
// latency is paid once per kc instead of once per ki (fc0 was at 1.65 TB/s
// effective with ~2 loads in flight). mode 0: h0/hs out; mode 2: fp32 out.

template <int AFP32, int MT>
__global__ __launch_bounds__(256) void k_gemm(
    const void* __restrict__ Av, const unsigned short* __restrict__ WT,
    int M, int K,
    const float* __restrict__ bias, const float* __restrict__ dinv,
    unsigned short* __restrict__ out0, unsigned short* __restrict__ out1,
    float* __restrict__ outf, int mode) {
    __shared__ __align__(16) unsigned short bt[128 * LDB];
    const int tid = threadIdx.x;
    const int w = tid >> 6, ln = tid & 63;
    const int quad = ln >> 4, l16 = ln & 15;
    const int ROWS = 64 * MT;
    const int block_base = blockIdx.x * ROWS;
    const int m_base = block_base + w * (16 * MT);

    f32x4 acc[MT][8];
#pragma unroll
    for (int i = 0; i < MT; i++)
#pragma unroll
        for (int j = 0; j < 8; j++) acc[i][j] = (f32x4){0.f, 0.f, 0.f, 0.f};

    for (int kc = 0; kc < K; kc += 128) {
        // issue ALL A loads for this kc block first (independent of LDS)
        float4 a_f[MT][4][2];
        short8 a_b[MT][4];
#pragma unroll
        for (int ki4 = 0; ki4 < 4; ki4++) {
#pragma unroll
            for (int mt = 0; mt < MT; mt++) {
                int row = m_base + mt * 16 + l16;
                if (row >= M) row = M - 1;
                if (AFP32) {
                    const float* A = (const float*)Av;
                    const float* p = &A[(size_t)row * K + kc + ki4 * 32 + quad * 8];
                    a_f[mt][ki4][0] = *(const float4*)p;
                    a_f[mt][ki4][1] = *(const float4*)(p + 4);
                } else {
                    const unsigned short* A = (const unsigned short*)Av;
                    a_b[mt][ki4] =
                        *(const short8*)&A[(size_t)row * K + kc + ki4 * 32 + quad * 8];
                }
            }
        }
        // stage WT chunk (loads overlap with the A loads above)
        for (int chunk = tid; chunk < 128 * 16; chunk += 256) {
            int n = chunk >> 4, k8 = (chunk & 15) << 3;
            *(short8*)&bt[n * LDB + k8] = *(const short8*)&WT[(size_t)n * K + kc + k8];
        }
        __syncthreads();
#pragma unroll
        for (int ki4 = 0; ki4 < 4; ki4++) {
            short8 bf[8];
#pragma unroll
            for (int nt = 0; nt < 8; nt++)
                bf[nt] = *(const short8*)&bt[(nt * 16 + l16) * LDB + ki4 * 32 + quad * 8];
#pragma unroll
            for (int mt = 0; mt < MT; mt++) {
                short8 af;
                if (AFP32) {
                    float4 f0 = a_f[mt][ki4][0];
                    float4 f1 = a_f[mt][ki4][1];
                    af[0] = (short)f2b(f0.x); af[1] = (short)f2b(f0.y);
                    af[2] = (short)f2b(f0.z); af[3] = (short)f2b(f0.w);
                    af[4] = (short)f2b(f1.x); af[5] = (short)f2b(f1.y);
                    af[6] = (short)f2b(f1.z); af[7] = (short)f2b(f1.w);
                } else {
                    af = a_b[mt][ki4];
                }
#pragma unroll
                for (int nt = 0; nt < 8; nt++)
                    acc[mt][nt] = __builtin_amdgcn_mfma_f32_16x16x32_bf16(
                        af, bf[nt], acc[mt][nt], 0, 0, 0);
            }
        }
        __syncthreads();
    }

    if (mode == 2) {
#pragma unroll
        for (int mt = 0; mt < MT; mt++)
#pragma unroll
            for (int reg = 0; reg < 4; reg++) {
                int r = m_base + mt * 16 + quad * 4 + reg;
                if (r >= M) continue;
#pragma unroll
                for (int nt = 0; nt < 8; nt++) {
                    int n = nt * 16 + l16;
                    outf[(size_t)r * NH_C + n] = acc[mt][nt][reg] + bias[n];
                }
            }
        return;
    }

    // mode 0: relu(acc+bias) -> LDS (own-wave rows) -> wave-private stores
#pragma unroll
    for (int mt = 0; mt < MT; mt++)
#pragma unroll
        for (int reg = 0; reg < 4; reg++) {
            int lr = w * (16 * MT) + mt * 16 + quad * 4 + reg;
#pragma unroll
            for (int nt = 0; nt < 8; nt++) {
                int n = nt * 16 + l16;
                float v = acc[mt][nt][reg] + bias[n];
                bt[lr * LDB + n] = f2b(fmaxf(v, 0.f));
            }
        }
    // no barrier: last kc sync already done; each wave reads only rows it wrote
#pragma unroll
    for (int it = 0; it < 4 * MT; it++) {
        int local = ln + it * 64;
        int lr = w * (16 * MT) + (local >> 4);
        int c8 = (local & 15) << 3;
        int row = block_base + lr;
        if (row >= M) continue;
        short8 v = *(const short8*)&bt[lr * LDB + c8];
        *(short8*)&out1[(size_t)row * NH_C + c8] = v;  // h0
        float dr = dinv[row];
        short8 o;
#pragma unroll
        for (int j = 0; j < 8; j++)
            o[j] = (short)f2b(b2f((unsigned short)v[j]) * dr);
        *(short8*)&out0[(size_t)row * NH_C + c8] = o;  // hs
    }
}

// ---------------- host ----------------

extern "C" void kernel_launch(void* const* d_in, const int* in_sizes, int n_in,
                              void* d_out, int out_size, void* d_ws, size_t ws_size,
                              hipStream_t stream) {
    const float* x = (const float*)d_in[0];
    const int* edge = (const int*)d_in[1];
    const float* convw = (const float*)d_in[2];
    const float* fc0w = (const float*)d_in[3];
    const float* fc0b = (const float*)d_in[4];
    const float* fc1w = (const float*)d_in[5];
    const float* fc1b = (const float*)d_in[6];
    const int* erow = edge;
    const int* ecol = edge + N_EDGES_C;

    char* ws = (char*)d_ws;
    size_t off = 0;
    auto alloc = [&](size_t bytes) -> void* {
        off = (off + 255) & ~(size_t)255;
        void* p = ws + off;
        off += bytes;
        return p;
    };
    int* cnt = (int*)alloc(N_NODES_C * 4);
    int* cursor = (int*)alloc(N_NODES_C * 4);
    int* locex = (int*)alloc(N_NODES_C * 4);
    int* partials = (int*)alloc(1024);
    int* rowptr = (int*)alloc((N_NODES_C + 1) * 4);
    float* dinv = (float*)alloc(N_NODES_C * 4);
    int* colsorted = (int*)alloc(N_EDGES_C * 4);
    unsigned short* wconvT = (unsigned short*)alloc((size_t)NLAYERS_C * NH_C * NH_C * 2);
    unsigned short* wfc0T = (unsigned short*)alloc((size_t)NFEAT_C * NH_C * 2);
    unsigned short* wfc1T = (unsigned short*)alloc((size_t)NH_C * NH_C * 2);
    unsigned short* h0 = (unsigned short*)alloc((size_t)N_NODES_C * NH_C * 2);
    unsigned short* hsA = (unsigned short*)alloc((size_t)N_NODES_C * NH_C * 2);
    unsigned short* hsB = (unsigned short*)alloc((size_t)N_NODES_C * NH_C * 2);
    unsigned short* sbuf = (unsigned short*)alloc((size_t)N_NODES_C * NH_C * 2);
    (void)ws_size; (void)n_in; (void)in_sizes; (void)out_size;

    // weights -> transposed bf16
    k_convt128<<<NLAYERS_C * NH_C * NH_C / 256, 256, 0, stream>>>(
        convw, wconvT, NLAYERS_C * NH_C * NH_C);
    k_convt_fc0<<<NFEAT_C * NH_C / 256, 256, 0, stream>>>(fc0w, wfc0T);
    k_convt128<<<NH_C * NH_C / 256, 256, 0, stream>>>(fc1w, wfc1T, NH_C * NH_C);

    // CSR build
    hipMemsetAsync(cnt, 0, N_NODES_C * 4, stream);
    k_count<<<N_EDGES_C / 256, 256, 0, stream>>>(erow, cnt);
    const int NB = (N_NODES_C + 255) / 256;  // 196
    k_scan1<<<NB, 256, 0, stream>>>(cnt, locex, partials, N_NODES_C);
    k_scan2<<<1, 256, 0, stream>>>(partials, NB);
    k_scan3<<<NB, 256, 0, stream>>>(cnt, locex, partials, rowptr, cursor, dinv,
                                    N_NODES_C, N_EDGES_C);
    k_fill<<<N_EDGES_C / 256, 256, 0, stream>>>(erow, ecol, cursor, colsorted);

    const int GB1 = (N_NODES_C + 63) / 64;    // 782
    // fc0: h0 = relu(x@fc0_w + b); hsA = dinv .* h0
    k_gemm<1, 1><<<GB1, 256, 0, stream>>>(x, wfc0T, N_NODES_C, NFEAT_C, fc0b, dinv,
                                          hsA, h0, nullptr, 0);
    unsigned short* cur = hsA;
    unsigned short* nxt = hsB;
    for (int l = 0; l < NLAYERS_C; l++) {
        k_spmm<<<N_NODES_C / 4, 256, 0, stream>>>(cur, h0, dinv, rowptr, colsorted,
                                                  sbuf);
        float theta = logf(0.5f / (float)(l + 1) + 1.0f);
        k_gemm_blend<<<GB1, 256, 0, stream>>>(sbuf, dinv,
                                              wconvT + (size_t)l * NH_C * NH_C, nxt,
                                              theta, (l < NLAYERS_C - 1) ? 1 : 0);
        unsigned short* t = cur; cur = nxt; nxt = t;
    }
    // fc1: out = h@fc1_w + b -> fp32
    k_gemm<0, 1><<<GB1, 256, 0, stream>>>(cur, wfc1T, N_NODES_C, NH_C, fc1b, dinv,
                                          nullptr, nullptr, (float*)d_out, 2);
}